// Round 8
// baseline (12530.568 us; speedup 1.0000x reference)
//
#include <hip/hip_runtime.h>
#include <hip/hip_bf16.h>

// ---------------------------------------------------------------------------
// Problem constants (reference: B,N,T,P,H = 256,101,128,4,16)
// ---------------------------------------------------------------------------
constexpr int B = 256;
constexpr int N = 101;
constexpr int T = 128;

typedef float vf2 __attribute__((ext_vector_type(2)));
typedef float vf4 __attribute__((ext_vector_type(4)));

__device__ __forceinline__ float frcp(float x) { return __builtin_amdgcn_rcpf(x); }
__device__ __forceinline__ float sigmoidf_(float x) { return frcp(1.f + __expf(-x)); }
// tanh(x) = 2*sigmoid(2x) - 1  (safe at large |x|)
__device__ __forceinline__ float tanhf_(float x) { return 2.f * frcp(1.f + __expf(-2.f * x)) - 1.f; }
__device__ __forceinline__ vf4 relu4(vf4 a) {
  a.x = fmaxf(a.x, 0.f); a.y = fmaxf(a.y, 0.f);
  a.z = fmaxf(a.z, 0.f); a.w = fmaxf(a.w, 0.f);
  return a;
}

// XCD-aware n-swizzle (kept for d12; harmless if dispatch heuristic wrong).
__device__ __forceinline__ int swz_n(int L) {
  int q = L & 7, r = L >> 3;
  return q * 13 - (q > 5 ? (q - 5) : 0) + r;
}

// ---------------------------------------------------------------------------
// K1: LSTM, 16 lanes per pair of (b,n) rows (2 rows packed in float2 ->
// v_pk_fma_f32). Weights in VGPRs, h broadcast via shfl. h_out: [B*N][16]
// ---------------------------------------------------------------------------
__global__ __launch_bounds__(256) void lstm_kernel(
    const float* __restrict__ x,     // [B][N][T][4]
    const float* __restrict__ pw,    // [4][4]
    const float* __restrict__ pb,    // [4]
    const float* __restrict__ w_ih,  // [64][4]
    const float* __restrict__ w_hh,  // [64][16]
    const float* __restrict__ b_ih,  // [64]
    const float* __restrict__ b_hh,  // [64]
    float* __restrict__ h_out) {
  const int tid = threadIdx.x;
  const int lane = tid & 63;
  const int sub = lane >> 4;   // row-pair within wave (0..3)
  const int k = lane & 15;     // hidden unit owned by this lane
  const int wave = tid >> 6;   // wave within block (0..3)
  const int row = blockIdx.x * 32 + wave * 8 + sub * 2;  // 808*32 = 25856

  float wih[4][4], whh[4][16], bias[4];
#pragma unroll
  for (int q = 0; q < 4; q++) {
    const int j = q * 16 + k;  // gate order i,f,g,o
    bias[q] = b_ih[j] + b_hh[j];
#pragma unroll
    for (int jj = 0; jj < 4; jj++) wih[q][jj] = w_ih[j * 4 + jj];
#pragma unroll
    for (int m = 0; m < 16; m++) whh[q][m] = w_hh[j * 16 + m];
  }
  float pwr[16], pbr[4];
#pragma unroll
  for (int i = 0; i < 16; i++) pwr[i] = pw[i];
#pragma unroll
  for (int i = 0; i < 4; i++) pbr[i] = pb[i];

  vf2 h = {0.f, 0.f}, c = {0.f, 0.f};
  const float4* xpA = (const float4*)x + (size_t)row * T;
  const float4* xpB = xpA + T;
  const int base = sub * 16;

#pragma unroll 1
  for (int t = 0; t < T; t++) {
    float4 xa = xpA[t];
    float4 xb = xpB[t];
    vf2 xv[4];
#pragma unroll
    for (int j = 0; j < 4; j++) {
      vf2 v = {pbr[j], pbr[j]};
      v += pwr[j * 4 + 0] * (vf2){xa.x, xb.x};
      v += pwr[j * 4 + 1] * (vf2){xa.y, xb.y};
      v += pwr[j * 4 + 2] * (vf2){xa.z, xb.z};
      v += pwr[j * 4 + 3] * (vf2){xa.w, xb.w};
      xv[j] = v;
    }
    vf2 a0 = {bias[0], bias[0]}, a1 = {bias[1], bias[1]};
    vf2 a2 = {bias[2], bias[2]}, a3 = {bias[3], bias[3]};
#pragma unroll
    for (int j = 0; j < 4; j++) {
      a0 += wih[0][j] * xv[j];
      a1 += wih[1][j] * xv[j];
      a2 += wih[2][j] * xv[j];
      a3 += wih[3][j] * xv[j];
    }
#pragma unroll
    for (int m = 0; m < 16; m++) {
      vf2 hm;
      hm.x = __shfl(h.x, base + m, 64);
      hm.y = __shfl(h.y, base + m, 64);
      a0 += whh[0][m] * hm;
      a1 += whh[1][m] * hm;
      a2 += whh[2][m] * hm;
      a3 += whh[3][m] * hm;
    }
    vf2 ig, fg, gg, og, tc;
    ig.x = sigmoidf_(a0.x); ig.y = sigmoidf_(a0.y);
    fg.x = sigmoidf_(a1.x); fg.y = sigmoidf_(a1.y);
    gg.x = tanhf_(a2.x);    gg.y = tanhf_(a2.y);
    og.x = sigmoidf_(a3.x); og.y = sigmoidf_(a3.y);
    c = fg * c + ig * gg;
    tc.x = tanhf_(c.x);     tc.y = tanhf_(c.y);
    h = og * tc;
  }
  h_out[(size_t)row * 16 + k] = h.x;
  h_out[(size_t)(row + 1) * 16 + k] = h.y;
}

// ---------------------------------------------------------------------------
// K2/K4/K6: fused d1(relu)+d2(relu), causal dilated 1x3 over T.
// Pure streaming, no LDS/barriers (R5-proven, at its VALU floor). Unchanged.
// ---------------------------------------------------------------------------
template <int CI, int CO, int DIL, bool FIRST>
__global__ __launch_bounds__(128) void d12_kernel(
    const float* __restrict__ xin,
    const float* __restrict__ pw, const float* __restrict__ pb,
    const float* __restrict__ w1,  // [CO][CI][3]
    const float* __restrict__ w2,  // [CO][CO][3]
    float* __restrict__ out, int b0) {
  const int t = threadIdx.x;  // 128 threads
  const int n = swz_n(blockIdx.x), by = blockIdx.y;

  float r1[3][CO];
#pragma unroll
  for (int u = 0; u < 3; u++)
#pragma unroll
    for (int co = 0; co < CO; co++) r1[u][co] = 0.f;

  if constexpr (FIRST) {
    const int b = b0 + by;
    const float4* xp = (const float4*)xin + ((size_t)b * N + n) * T;
    float px[5][4];
#pragma unroll
    for (int v = 0; v < 5; v++) {
      int idx = t - v * DIL;
      float4 xr = xp[idx < 0 ? 0 : idx];
      bool ok = idx >= 0;
      px[v][0] = ok ? pb[0] + pw[0] * xr.x + pw[1] * xr.y + pw[2] * xr.z + pw[3] * xr.w : 0.f;
      px[v][1] = ok ? pb[1] + pw[4] * xr.x + pw[5] * xr.y + pw[6] * xr.z + pw[7] * xr.w : 0.f;
      px[v][2] = ok ? pb[2] + pw[8] * xr.x + pw[9] * xr.y + pw[10] * xr.z + pw[11] * xr.w : 0.f;
      px[v][3] = ok ? pb[3] + pw[12] * xr.x + pw[13] * xr.y + pw[14] * xr.z + pw[15] * xr.w : 0.f;
    }
#pragma unroll
    for (int ci = 0; ci < CI; ci++) {
#pragma unroll
      for (int j = 0; j < 3; j++) {
#pragma unroll
        for (int co = 0; co < CO; co++) {
          float w = w1[(co * CI + ci) * 3 + j];
#pragma unroll
          for (int u = 0; u < 3; u++) r1[u][co] += w * px[u + 2 - j][ci];
        }
      }
    }
  } else {
#pragma unroll
    for (int ci = 0; ci < CI; ci++) {
      const float* xp = xin + (((size_t)by * CI + ci) * N + n) * T;
      float xt[5];
#pragma unroll
      for (int v = 0; v < 5; v++) {
        int idx = t - v * DIL;
        float xv = xp[idx < 0 ? 0 : idx];
        xt[v] = (idx >= 0) ? xv : 0.f;
      }
#pragma unroll
      for (int j = 0; j < 3; j++) {
#pragma unroll
        for (int co = 0; co < CO; co++) {
          float w = w1[(co * CI + ci) * 3 + j];
#pragma unroll
          for (int u = 0; u < 3; u++) r1[u][co] += w * xt[u + 2 - j];
        }
      }
    }
  }

#pragma unroll
  for (int u = 0; u < 3; u++)
#pragma unroll
    for (int co = 0; co < CO; co++) r1[u][co] = fmaxf(r1[u][co], 0.f);

  float acc[CO];
#pragma unroll
  for (int co = 0; co < CO; co++) acc[co] = 0.f;
#pragma unroll
  for (int cm = 0; cm < CO; cm++) {
#pragma unroll
    for (int j = 0; j < 3; j++) {
#pragma unroll
      for (int co = 0; co < CO; co++) {
        float w = w2[(co * CO + cm) * 3 + j];
        acc[co] += w * r1[2 - j][cm];
      }
    }
  }
#pragma unroll
  for (int co = 0; co < CO; co++)
    out[(((size_t)by * CO + co) * N + n) * T + t] = fmaxf(acc[co], 0.f);
}

// ---------------------------------------------------------------------------
// K3/K5/K7: cross-stock 11x1 conv over N + residual + relus.
// NEW: each thread owns a t-QUAD (float4): 128 threads = 4 n x 32 t-quads.
// FMA:load ratio 16 -> 64, so per-dn load latency hides under 2048 FMA
// cycles (cc was latency-bound: R7 cut FETCH 4x with no dur change).
// FUSEC4: conv4 reduced per 32-lane group via shfl (width 32) -- no LDS,
// no barrier, no atomics; h4 written relu'd directly.
// ---------------------------------------------------------------------------
template <int C, int CIR, int RESMODE, bool FUSEC4>
__global__ __launch_bounds__(128) void cc_kernel(
    const float* __restrict__ zin,    // chunk [Bc][C][N][T]
    const float* __restrict__ ccw,    // [C][C][11]
    const float* __restrict__ resin,  // RESMODE 0: x global; else chunk buffer
    const float* __restrict__ rw,     // [C][CIR] or null
    const float* __restrict__ pw, const float* __restrict__ pb,
    float* __restrict__ out,          // chunk [Bc][C][N][T] or null
    const float* __restrict__ w4,     // [16][16][T] or null
    float* __restrict__ h4,           // [B][16][N] or null
    int b0) {
  const int tid = threadIdx.x;       // 128 threads
  const int tq = tid & 31;           // t-quad index; t = 4*tq..4*tq+3
  const int nl = tid >> 5;           // 0..3
  const int n = blockIdx.x * 4 + nl;
  const int by = blockIdx.y;
  const int b = b0 + by;
  const bool nvalid = n < N;
  const int nc = nvalid ? n : 0;
  const int t0 = tq * 4;

  vf4 acc[C];
#pragma unroll
  for (int co = 0; co < C; co++) acc[co] = (vf4)0.f;

#pragma unroll
  for (int dn = 0; dn < 11; dn++) {
    int nn = nc + dn - 5;
    bool ok = nvalid && (unsigned)nn < (unsigned)N;
    int nni = ok ? nn : 0;
#pragma unroll
    for (int ci = 0; ci < C; ci++) {
      vf4 v = *(const vf4*)&zin[(((size_t)by * C + ci) * N + nni) * T + t0];
      if (!ok) v = (vf4)0.f;
#pragma unroll
      for (int co = 0; co < C; co++)
        acc[co] += ccw[(co * C + ci) * 11 + dn] * v;
    }
  }

#pragma unroll
  for (int co = 0; co < C; co++) acc[co] = relu4(acc[co]);  // relu(conv)

  // residual added into acc, then final relu
  if constexpr (RESMODE == 0) {
    const vf4* xp = (const vf4*)resin + ((size_t)b * N + nc) * T;
    vf4 xr0 = xp[t0], xr1 = xp[t0 + 1], xr2 = xp[t0 + 2], xr3 = xp[t0 + 3];
    vf4 xx = {xr0.x, xr1.x, xr2.x, xr3.x};
    vf4 xy = {xr0.y, xr1.y, xr2.y, xr3.y};
    vf4 xz = {xr0.z, xr1.z, xr2.z, xr3.z};
    vf4 xw = {xr0.w, xr1.w, xr2.w, xr3.w};
    vf4 xv[4];
#pragma unroll
    for (int j = 0; j < 4; j++)
      xv[j] = pb[j] + pw[j * 4 + 0] * xx + pw[j * 4 + 1] * xy +
              pw[j * 4 + 2] * xz + pw[j * 4 + 3] * xw;
#pragma unroll
    for (int ci = 0; ci < 4; ci++)
#pragma unroll
      for (int co = 0; co < C; co++) acc[co] += rw[co * 4 + ci] * xv[ci];
  } else if constexpr (RESMODE == 1) {
#pragma unroll
    for (int ci = 0; ci < CIR; ci++) {
      vf4 v = *(const vf4*)&resin[(((size_t)by * CIR + ci) * N + nc) * T + t0];
#pragma unroll
      for (int co = 0; co < C; co++) acc[co] += rw[co * CIR + ci] * v;
    }
  } else {
#pragma unroll
    for (int co = 0; co < C; co++) {
      vf4 v = *(const vf4*)&resin[(((size_t)by * C + co) * N + nc) * T + t0];
      acc[co] += v;
    }
  }
#pragma unroll
  for (int co = 0; co < C; co++) acc[co] = relu4(acc[co]);  // y

  if constexpr (!FUSEC4) {
    if (nvalid) {
#pragma unroll
      for (int co = 0; co < C; co++)
        *(vf4*)&out[(((size_t)by * C + co) * N + n) * T + t0] = acc[co];
    }
  } else {
    // conv4: h4[b][o][n] = relu(sum_{ci,t} w4[o][ci][t] * y[ci][t]).
    // Each 32-lane group covers the full T for one n.
#pragma unroll
    for (int o = 0; o < 16; o++) {
      vf4 s = (vf4)0.f;
#pragma unroll
      for (int ci = 0; ci < 16; ci++) {
        vf4 w = *(const vf4*)&w4[(size_t)(o * 16 + ci) * T + t0];
        s += w * acc[ci];
      }
      float sum = (s.x + s.y) + (s.z + s.w);
      sum += __shfl_down(sum, 16, 32);
      sum += __shfl_down(sum, 8, 32);
      sum += __shfl_down(sum, 4, 32);
      sum += __shfl_down(sum, 2, 32);
      sum += __shfl_down(sum, 1, 32);
      if (tq == 0 && nvalid)
        h4[((size_t)b * 16 + o) * N + n] = fmaxf(sum, 0.f);
    }
  }
}

// ---------------------------------------------------------------------------
// K8: logits (with torch's reshape scramble of h_last) + softmax over N
// ---------------------------------------------------------------------------
__global__ __launch_bounds__(128) void final_kernel(
    const float* __restrict__ hl,  // [B*N][16]
    const float* __restrict__ h4,  // [B][16][N] (already relu'd)
    const float* __restrict__ ow,  // [32]
    const float* __restrict__ ob,  // [1]
    float* __restrict__ out) {     // [B][N]
  __shared__ float red[128];
  int b = blockIdx.x, n = threadIdx.x;  // 128 threads
  bool valid = n < N;
  float lv = 0.f;
  if (valid) {
    int idx = b * N + n;
    int sb = idx & (B - 1);
    int sn = idx >> 8;
    const float* h = &hl[((size_t)sb * N + sn) * 16];
    float a = ob[0];
#pragma unroll
    for (int k = 0; k < 16; k++) a += h[k] * ow[k];
#pragma unroll
    for (int c = 0; c < 16; c++) a += h4[((size_t)b * 16 + c) * N + n] * ow[16 + c];
    lv = a;
  }
  red[n] = valid ? lv : -1e30f;
  __syncthreads();
  for (int off = 64; off > 0; off >>= 1) {
    if (n < off) red[n] = fmaxf(red[n], red[n + off]);
    __syncthreads();
  }
  float m = red[0];
  __syncthreads();
  float e = valid ? __expf(lv - m) : 0.f;
  red[n] = e;
  __syncthreads();
  for (int off = 64; off > 0; off >>= 1) {
    if (n < off) red[n] += red[n + off];
    __syncthreads();
  }
  float s = red[0];
  if (valid) out[(size_t)b * N + n] = e / s;
}

// ---------------------------------------------------------------------------
// Launch. Conv pipeline chunked over B to fit whatever ws_size we're given.
// ---------------------------------------------------------------------------
extern "C" void kernel_launch(void* const* d_in, const int* in_sizes, int n_in,
                              void* d_out, int out_size, void* d_ws, size_t ws_size,
                              hipStream_t stream) {
  const float* x    = (const float*)d_in[0];
  const float* pw   = (const float*)d_in[1];
  const float* pb   = (const float*)d_in[2];
  const float* w_ih = (const float*)d_in[3];
  const float* w_hh = (const float*)d_in[4];
  const float* b_ih = (const float*)d_in[5];
  const float* b_hh = (const float*)d_in[6];
  const float* t1d1 = (const float*)d_in[7];
  const float* t1d2 = (const float*)d_in[8];
  const float* t1c  = (const float*)d_in[9];
  const float* t1r  = (const float*)d_in[10];
  const float* t2d1 = (const float*)d_in[11];
  const float* t2d2 = (const float*)d_in[12];
  const float* t2c  = (const float*)d_in[13];
  const float* t2r  = (const float*)d_in[14];
  const float* t3d1 = (const float*)d_in[15];
  const float* t3d2 = (const float*)d_in[16];
  const float* t3c  = (const float*)d_in[17];
  const float* w4   = (const float*)d_in[18];
  const float* ow   = (const float*)d_in[19];
  const float* ob   = (const float*)d_in[20];
  float* outp = (float*)d_out;

  const size_t NT = (size_t)N * T;          // 12928
  const size_t unit = 40 * NT;              // floats per chunked b
  const size_t fixed = 2 * (size_t)B * N * 16;

  int Bc = 4;
  const int cands[7] = {256, 128, 64, 32, 16, 8, 4};
  for (int i = 0; i < 7; i++) {
    if ((cands[i] * unit + fixed) * sizeof(float) <= ws_size) { Bc = cands[i]; break; }
  }

  float* ws = (float*)d_ws;
  float* hl = ws;                      // [B*N][16]
  float* h4 = hl + (size_t)B * N * 16; // [B][16][N]
  float* H1 = h4 + (size_t)B * 16 * N; // [Bc][8][N][T]
  float* Tb = H1 + (size_t)Bc * 8 * NT;   // [Bc][16][N][T]
  float* H2 = Tb + (size_t)Bc * 16 * NT;  // [Bc][16][N][T]

  lstm_kernel<<<(B * N) / 32, 256, 0, stream>>>(x, pw, pb, w_ih, w_hh, b_ih,
                                                b_hh, hl);

  dim3 g(N, Bc);
  dim3 gcc((N + 3) / 4, Bc);  // 26 x Bc
  for (int b0 = 0; b0 < B; b0 += Bc) {
    d12_kernel<4, 8, 1, true>
        <<<g, 128, 0, stream>>>(x, pw, pb, t1d1, t1d2, Tb, b0);
    cc_kernel<8, 4, 0, false><<<gcc, 128, 0, stream>>>(
        Tb, t1c, x, t1r, pw, pb, H1, nullptr, nullptr, b0);

    d12_kernel<8, 16, 2, false>
        <<<g, 128, 0, stream>>>(H1, pw, pb, t2d1, t2d2, Tb, b0);
    cc_kernel<16, 8, 1, false><<<gcc, 128, 0, stream>>>(
        Tb, t2c, H1, t2r, pw, pb, H2, nullptr, nullptr, b0);

    d12_kernel<16, 16, 4, false>
        <<<g, 128, 0, stream>>>(H2, pw, pb, t3d1, t3d2, Tb, b0);
    cc_kernel<16, 16, 2, true><<<gcc, 128, 0, stream>>>(
        Tb, t3c, H2, nullptr, pw, pb, nullptr, w4, h4, b0);
  }

  final_kernel<<<B, 128, 0, stream>>>(hl, h4, ow, ob, outp);
}

// Round 9
// 1885.968 us; speedup vs baseline: 6.6441x; 6.6441x over previous
//
#include <hip/hip_runtime.h>
#include <hip/hip_bf16.h>

// ---------------------------------------------------------------------------
// Problem constants (reference: B,N,T,P,H = 256,101,128,4,16)
// ---------------------------------------------------------------------------
constexpr int B = 256;
constexpr int N = 101;
constexpr int T = 128;

typedef float vf2 __attribute__((ext_vector_type(2)));

__device__ __forceinline__ float frcp(float x) { return __builtin_amdgcn_rcpf(x); }
__device__ __forceinline__ float sigmoidf_(float x) { return frcp(1.f + __expf(-x)); }
// tanh(x) = 2*sigmoid(2x) - 1  (safe at large |x|)
__device__ __forceinline__ float tanhf_(float x) { return 2.f * frcp(1.f + __expf(-2.f * x)) - 1.f; }
__device__ __forceinline__ vf2 relu2(vf2 a) {
  a.x = fmaxf(a.x, 0.f); a.y = fmaxf(a.y, 0.f);
  return a;
}

// XCD-aware n-swizzle (R7: cut cc FETCH 605->140 MB). Bijection on [0,101).
__device__ __forceinline__ int swz_n(int L) {
  int q = L & 7, r = L >> 3;
  return q * 13 - (q > 5 ? (q - 5) : 0) + r;
}

// ---------------------------------------------------------------------------
// K1: LSTM, 16 lanes per pair of (b,n) rows (2 rows packed in float2 ->
// v_pk_fma_f32). Weights in VGPRs, h broadcast via shfl. h_out: [B*N][16]
// ---------------------------------------------------------------------------
__global__ __launch_bounds__(256) void lstm_kernel(
    const float* __restrict__ x,     // [B][N][T][4]
    const float* __restrict__ pw,    // [4][4]
    const float* __restrict__ pb,    // [4]
    const float* __restrict__ w_ih,  // [64][4]
    const float* __restrict__ w_hh,  // [64][16]
    const float* __restrict__ b_ih,  // [64]
    const float* __restrict__ b_hh,  // [64]
    float* __restrict__ h_out) {
  const int tid = threadIdx.x;
  const int lane = tid & 63;
  const int sub = lane >> 4;   // row-pair within wave (0..3)
  const int k = lane & 15;     // hidden unit owned by this lane
  const int wave = tid >> 6;   // wave within block (0..3)
  const int row = blockIdx.x * 32 + wave * 8 + sub * 2;  // 808*32 = 25856

  float wih[4][4], whh[4][16], bias[4];
#pragma unroll
  for (int q = 0; q < 4; q++) {
    const int j = q * 16 + k;  // gate order i,f,g,o
    bias[q] = b_ih[j] + b_hh[j];
#pragma unroll
    for (int jj = 0; jj < 4; jj++) wih[q][jj] = w_ih[j * 4 + jj];
#pragma unroll
    for (int m = 0; m < 16; m++) whh[q][m] = w_hh[j * 16 + m];
  }
  float pwr[16], pbr[4];
#pragma unroll
  for (int i = 0; i < 16; i++) pwr[i] = pw[i];
#pragma unroll
  for (int i = 0; i < 4; i++) pbr[i] = pb[i];

  vf2 h = {0.f, 0.f}, c = {0.f, 0.f};
  const float4* xpA = (const float4*)x + (size_t)row * T;
  const float4* xpB = xpA + T;
  const int base = sub * 16;

#pragma unroll 1
  for (int t = 0; t < T; t++) {
    float4 xa = xpA[t];
    float4 xb = xpB[t];
    vf2 xv[4];
#pragma unroll
    for (int j = 0; j < 4; j++) {
      vf2 v = {pbr[j], pbr[j]};
      v += pwr[j * 4 + 0] * (vf2){xa.x, xb.x};
      v += pwr[j * 4 + 1] * (vf2){xa.y, xb.y};
      v += pwr[j * 4 + 2] * (vf2){xa.z, xb.z};
      v += pwr[j * 4 + 3] * (vf2){xa.w, xb.w};
      xv[j] = v;
    }
    vf2 a0 = {bias[0], bias[0]}, a1 = {bias[1], bias[1]};
    vf2 a2 = {bias[2], bias[2]}, a3 = {bias[3], bias[3]};
#pragma unroll
    for (int j = 0; j < 4; j++) {
      a0 += wih[0][j] * xv[j];
      a1 += wih[1][j] * xv[j];
      a2 += wih[2][j] * xv[j];
      a3 += wih[3][j] * xv[j];
    }
#pragma unroll
    for (int m = 0; m < 16; m++) {
      vf2 hm;
      hm.x = __shfl(h.x, base + m, 64);
      hm.y = __shfl(h.y, base + m, 64);
      a0 += whh[0][m] * hm;
      a1 += whh[1][m] * hm;
      a2 += whh[2][m] * hm;
      a3 += whh[3][m] * hm;
    }
    vf2 ig, fg, gg, og, tc;
    ig.x = sigmoidf_(a0.x); ig.y = sigmoidf_(a0.y);
    fg.x = sigmoidf_(a1.x); fg.y = sigmoidf_(a1.y);
    gg.x = tanhf_(a2.x);    gg.y = tanhf_(a2.y);
    og.x = sigmoidf_(a3.x); og.y = sigmoidf_(a3.y);
    c = fg * c + ig * gg;
    tc.x = tanhf_(c.x);     tc.y = tanhf_(c.y);
    h = og * tc;
  }
  h_out[(size_t)row * 16 + k] = h.x;
  h_out[(size_t)(row + 1) * 16 + k] = h.y;
}

// ---------------------------------------------------------------------------
// K2/K4/K6: fused d1(relu)+d2(relu), causal dilated 1x3 over T.
// Pure streaming, no LDS/barriers (R5-proven, at its VALU floor). Unchanged.
// ---------------------------------------------------------------------------
template <int CI, int CO, int DIL, bool FIRST>
__global__ __launch_bounds__(128) void d12_kernel(
    const float* __restrict__ xin,
    const float* __restrict__ pw, const float* __restrict__ pb,
    const float* __restrict__ w1,  // [CO][CI][3]
    const float* __restrict__ w2,  // [CO][CO][3]
    float* __restrict__ out, int b0) {
  const int t = threadIdx.x;  // 128 threads
  const int n = swz_n(blockIdx.x), by = blockIdx.y;

  float r1[3][CO];
#pragma unroll
  for (int u = 0; u < 3; u++)
#pragma unroll
    for (int co = 0; co < CO; co++) r1[u][co] = 0.f;

  if constexpr (FIRST) {
    const int b = b0 + by;
    const float4* xp = (const float4*)xin + ((size_t)b * N + n) * T;
    float px[5][4];
#pragma unroll
    for (int v = 0; v < 5; v++) {
      int idx = t - v * DIL;
      float4 xr = xp[idx < 0 ? 0 : idx];
      bool ok = idx >= 0;
      px[v][0] = ok ? pb[0] + pw[0] * xr.x + pw[1] * xr.y + pw[2] * xr.z + pw[3] * xr.w : 0.f;
      px[v][1] = ok ? pb[1] + pw[4] * xr.x + pw[5] * xr.y + pw[6] * xr.z + pw[7] * xr.w : 0.f;
      px[v][2] = ok ? pb[2] + pw[8] * xr.x + pw[9] * xr.y + pw[10] * xr.z + pw[11] * xr.w : 0.f;
      px[v][3] = ok ? pb[3] + pw[12] * xr.x + pw[13] * xr.y + pw[14] * xr.z + pw[15] * xr.w : 0.f;
    }
#pragma unroll
    for (int ci = 0; ci < CI; ci++) {
#pragma unroll
      for (int j = 0; j < 3; j++) {
#pragma unroll
        for (int co = 0; co < CO; co++) {
          float w = w1[(co * CI + ci) * 3 + j];
#pragma unroll
          for (int u = 0; u < 3; u++) r1[u][co] += w * px[u + 2 - j][ci];
        }
      }
    }
  } else {
#pragma unroll
    for (int ci = 0; ci < CI; ci++) {
      const float* xp = xin + (((size_t)by * CI + ci) * N + n) * T;
      float xt[5];
#pragma unroll
      for (int v = 0; v < 5; v++) {
        int idx = t - v * DIL;
        float xv = xp[idx < 0 ? 0 : idx];
        xt[v] = (idx >= 0) ? xv : 0.f;
      }
#pragma unroll
      for (int j = 0; j < 3; j++) {
#pragma unroll
        for (int co = 0; co < CO; co++) {
          float w = w1[(co * CI + ci) * 3 + j];
#pragma unroll
          for (int u = 0; u < 3; u++) r1[u][co] += w * xt[u + 2 - j];
        }
      }
    }
  }

#pragma unroll
  for (int u = 0; u < 3; u++)
#pragma unroll
    for (int co = 0; co < CO; co++) r1[u][co] = fmaxf(r1[u][co], 0.f);

  float acc[CO];
#pragma unroll
  for (int co = 0; co < CO; co++) acc[co] = 0.f;
#pragma unroll
  for (int cm = 0; cm < CO; cm++) {
#pragma unroll
    for (int j = 0; j < 3; j++) {
#pragma unroll
      for (int co = 0; co < CO; co++) {
        float w = w2[(co * CO + cm) * 3 + j];
        acc[co] += w * r1[2 - j][cm];
      }
    }
  }
#pragma unroll
  for (int co = 0; co < CO; co++)
    out[(((size_t)by * CO + co) * N + n) * T + t] = fmaxf(acc[co], 0.f);
}

// ---------------------------------------------------------------------------
// K3/K5/K7: cross-stock 11x1 conv over N + residual + relus.
// R9: one 64-thread wave per (b,n); each thread owns a t-PAIR (vf2 ->
// v_pk_fma_f32). acc[16] = 32 VGPR (the R8 vf4 version hit the 256-VGPR
// ceiling and spilled 5.6 GB). dn loop: branch-free range [dnlo,dnhi),
// #pragma unroll 1 so loads stay batched per-dn (no mass hoisting).
// FUSEC4: conv4 via width-64 shfl reduce; h4 written relu'd, no LDS/atomics.
// ---------------------------------------------------------------------------
template <int C, int CIR, int RESMODE, bool FUSEC4>
__global__ __launch_bounds__(64) void cc_kernel(
    const float* __restrict__ zin,    // chunk [Bc][C][N][T]
    const float* __restrict__ ccw,    // [C][C][11]
    const float* __restrict__ resin,  // RESMODE 0: x global; else chunk buffer
    const float* __restrict__ rw,     // [C][CIR] or null
    const float* __restrict__ pw, const float* __restrict__ pb,
    float* __restrict__ out,          // chunk [Bc][C][N][T] or null
    const float* __restrict__ w4,     // [16][16][T] or null
    float* __restrict__ h4,           // [B][16][N] or null
    int b0) {
  const int tl = threadIdx.x;        // 0..63, t-pair index
  const int n = swz_n(blockIdx.x);
  const int by = blockIdx.y;
  const int b = b0 + by;
  const int t0 = tl * 2;

  const int dnlo = (n < 5) ? (5 - n) : 0;
  const int dnhi = (n > N - 6) ? (N + 5 - n) : 11;

  vf2 acc[C];
#pragma unroll
  for (int co = 0; co < C; co++) acc[co] = (vf2)0.f;

#pragma unroll 1
  for (int dn = dnlo; dn < dnhi; dn++) {
    const int nn = n + dn - 5;
    vf2 v[C];
#pragma unroll
    for (int ci = 0; ci < C; ci++)
      v[ci] = *(const vf2*)&zin[(((size_t)by * C + ci) * N + nn) * T + t0];
#pragma unroll
    for (int ci = 0; ci < C; ci++) {
#pragma unroll
      for (int co = 0; co < C; co++)
        acc[co] += ccw[(co * C + ci) * 11 + dn] * v[ci];
    }
  }

#pragma unroll
  for (int co = 0; co < C; co++) acc[co] = relu2(acc[co]);  // relu(conv)

  // residual added into acc, then final relu
  if constexpr (RESMODE == 0) {
    const vf2* xp = (const vf2*)resin + (((size_t)b * N + n) * T + t0) * 2;
    // x is [B][N][T][4]; element (t0+u) occupies 2 vf2 at offset 2*(t0+u)
    vf2 e0a = xp[0], e0b = xp[1], e1a = xp[2], e1b = xp[3];
    // per-channel across the t-pair: ch0={e0a.x,e1a.x} ch1={e0a.y,e1a.y}
    vf2 xch[4];
    xch[0] = (vf2){e0a.x, e1a.x};
    xch[1] = (vf2){e0a.y, e1a.y};
    xch[2] = (vf2){e0b.x, e1b.x};
    xch[3] = (vf2){e0b.y, e1b.y};
    vf2 xv[4];
#pragma unroll
    for (int j = 0; j < 4; j++)
      xv[j] = pb[j] + pw[j * 4 + 0] * xch[0] + pw[j * 4 + 1] * xch[1] +
              pw[j * 4 + 2] * xch[2] + pw[j * 4 + 3] * xch[3];
#pragma unroll
    for (int ci = 0; ci < 4; ci++)
#pragma unroll
      for (int co = 0; co < C; co++) acc[co] += rw[co * 4 + ci] * xv[ci];
  } else if constexpr (RESMODE == 1) {
#pragma unroll
    for (int ci = 0; ci < CIR; ci++) {
      vf2 v = *(const vf2*)&resin[(((size_t)by * CIR + ci) * N + n) * T + t0];
#pragma unroll
      for (int co = 0; co < C; co++) acc[co] += rw[co * CIR + ci] * v;
    }
  } else {
#pragma unroll
    for (int co = 0; co < C; co++) {
      vf2 v = *(const vf2*)&resin[(((size_t)by * C + co) * N + n) * T + t0];
      acc[co] += v;
    }
  }
#pragma unroll
  for (int co = 0; co < C; co++) acc[co] = relu2(acc[co]);  // y

  if constexpr (!FUSEC4) {
#pragma unroll
    for (int co = 0; co < C; co++)
      *(vf2*)&out[(((size_t)by * C + co) * N + n) * T + t0] = acc[co];
  } else {
    // conv4: h4[b][o][n] = relu(sum_{ci,t} w4[o][ci][t] * y[ci][t]).
    // This wave covers the full T for its n.
#pragma unroll 1
    for (int o = 0; o < 16; o++) {
      vf2 s = (vf2)0.f;
#pragma unroll
      for (int ci = 0; ci < 16; ci++) {
        vf2 w = *(const vf2*)&w4[(size_t)(o * 16 + ci) * T + t0];
        s += w * acc[ci];
      }
      float sum = s.x + s.y;
      sum += __shfl_down(sum, 32);
      sum += __shfl_down(sum, 16);
      sum += __shfl_down(sum, 8);
      sum += __shfl_down(sum, 4);
      sum += __shfl_down(sum, 2);
      sum += __shfl_down(sum, 1);
      if (tl == 0)
        h4[((size_t)b * 16 + o) * N + n] = fmaxf(sum, 0.f);
    }
  }
}

// ---------------------------------------------------------------------------
// K8: logits (with torch's reshape scramble of h_last) + softmax over N
// ---------------------------------------------------------------------------
__global__ __launch_bounds__(128) void final_kernel(
    const float* __restrict__ hl,  // [B*N][16]
    const float* __restrict__ h4,  // [B][16][N] (already relu'd)
    const float* __restrict__ ow,  // [32]
    const float* __restrict__ ob,  // [1]
    float* __restrict__ out) {     // [B][N]
  __shared__ float red[128];
  int b = blockIdx.x, n = threadIdx.x;  // 128 threads
  bool valid = n < N;
  float lv = 0.f;
  if (valid) {
    int idx = b * N + n;
    int sb = idx & (B - 1);
    int sn = idx >> 8;
    const float* h = &hl[((size_t)sb * N + sn) * 16];
    float a = ob[0];
#pragma unroll
    for (int k = 0; k < 16; k++) a += h[k] * ow[k];
#pragma unroll
    for (int c = 0; c < 16; c++) a += h4[((size_t)b * 16 + c) * N + n] * ow[16 + c];
    lv = a;
  }
  red[n] = valid ? lv : -1e30f;
  __syncthreads();
  for (int off = 64; off > 0; off >>= 1) {
    if (n < off) red[n] = fmaxf(red[n], red[n + off]);
    __syncthreads();
  }
  float m = red[0];
  __syncthreads();
  float e = valid ? __expf(lv - m) : 0.f;
  red[n] = e;
  __syncthreads();
  for (int off = 64; off > 0; off >>= 1) {
    if (n < off) red[n] += red[n + off];
    __syncthreads();
  }
  float s = red[0];
  if (valid) out[(size_t)b * N + n] = e / s;
}

// ---------------------------------------------------------------------------
// Launch. Conv pipeline chunked over B to fit whatever ws_size we're given.
// ---------------------------------------------------------------------------
extern "C" void kernel_launch(void* const* d_in, const int* in_sizes, int n_in,
                              void* d_out, int out_size, void* d_ws, size_t ws_size,
                              hipStream_t stream) {
  const float* x    = (const float*)d_in[0];
  const float* pw   = (const float*)d_in[1];
  const float* pb   = (const float*)d_in[2];
  const float* w_ih = (const float*)d_in[3];
  const float* w_hh = (const float*)d_in[4];
  const float* b_ih = (const float*)d_in[5];
  const float* b_hh = (const float*)d_in[6];
  const float* t1d1 = (const float*)d_in[7];
  const float* t1d2 = (const float*)d_in[8];
  const float* t1c  = (const float*)d_in[9];
  const float* t1r  = (const float*)d_in[10];
  const float* t2d1 = (const float*)d_in[11];
  const float* t2d2 = (const float*)d_in[12];
  const float* t2c  = (const float*)d_in[13];
  const float* t2r  = (const float*)d_in[14];
  const float* t3d1 = (const float*)d_in[15];
  const float* t3d2 = (const float*)d_in[16];
  const float* t3c  = (const float*)d_in[17];
  const float* w4   = (const float*)d_in[18];
  const float* ow   = (const float*)d_in[19];
  const float* ob   = (const float*)d_in[20];
  float* outp = (float*)d_out;

  const size_t NT = (size_t)N * T;          // 12928
  const size_t unit = 40 * NT;              // floats per chunked b
  const size_t fixed = 2 * (size_t)B * N * 16;

  int Bc = 4;
  const int cands[7] = {256, 128, 64, 32, 16, 8, 4};
  for (int i = 0; i < 7; i++) {
    if ((cands[i] * unit + fixed) * sizeof(float) <= ws_size) { Bc = cands[i]; break; }
  }

  float* ws = (float*)d_ws;
  float* hl = ws;                      // [B*N][16]
  float* h4 = hl + (size_t)B * N * 16; // [B][16][N]
  float* H1 = h4 + (size_t)B * 16 * N; // [Bc][8][N][T]
  float* Tb = H1 + (size_t)Bc * 8 * NT;   // [Bc][16][N][T]
  float* H2 = Tb + (size_t)Bc * 16 * NT;  // [Bc][16][N][T]

  lstm_kernel<<<(B * N) / 32, 256, 0, stream>>>(x, pw, pb, w_ih, w_hh, b_ih,
                                                b_hh, hl);

  dim3 g(N, Bc);
  for (int b0 = 0; b0 < B; b0 += Bc) {
    d12_kernel<4, 8, 1, true>
        <<<g, 128, 0, stream>>>(x, pw, pb, t1d1, t1d2, Tb, b0);
    cc_kernel<8, 4, 0, false><<<g, 64, 0, stream>>>(
        Tb, t1c, x, t1r, pw, pb, H1, nullptr, nullptr, b0);

    d12_kernel<8, 16, 2, false>
        <<<g, 128, 0, stream>>>(H1, pw, pb, t2d1, t2d2, Tb, b0);
    cc_kernel<16, 8, 1, false><<<g, 64, 0, stream>>>(
        Tb, t2c, H1, t2r, pw, pb, H2, nullptr, nullptr, b0);

    d12_kernel<16, 16, 4, false>
        <<<g, 128, 0, stream>>>(H2, pw, pb, t3d1, t3d2, Tb, b0);
    cc_kernel<16, 16, 2, true><<<g, 64, 0, stream>>>(
        Tb, t3c, H2, nullptr, pw, pb, nullptr, w4, h4, b0);
  }

  final_kernel<<<B, 128, 0, stream>>>(hl, h4, ow, ob, outp);
}

// Round 10
// 1511.412 us; speedup vs baseline: 8.2906x; 1.2478x over previous
//
#include <hip/hip_runtime.h>
#include <hip/hip_bf16.h>

// ---------------------------------------------------------------------------
// Problem constants (reference: B,N,T,P,H = 256,101,128,4,16)
// ---------------------------------------------------------------------------
constexpr int B = 256;
constexpr int N = 101;
constexpr int T = 128;

typedef float vf2 __attribute__((ext_vector_type(2)));
typedef short s8v __attribute__((ext_vector_type(8)));    // 8 bf16 (4 VGPRs)
typedef unsigned short u8v __attribute__((ext_vector_type(8)));
typedef float f4v __attribute__((ext_vector_type(4)));    // MFMA accum

__device__ __forceinline__ float frcp(float x) { return __builtin_amdgcn_rcpf(x); }
__device__ __forceinline__ float sigmoidf_(float x) { return frcp(1.f + __expf(-x)); }
__device__ __forceinline__ float tanhf_(float x) { return 2.f * frcp(1.f + __expf(-2.f * x)) - 1.f; }

// fp32 -> bf16 bits, round-nearest-even
__device__ __forceinline__ unsigned short f2bf(float x) {
  unsigned int u = __float_as_uint(x);
  u = (u + 0x7FFFu + ((u >> 16) & 1u)) >> 16;
  return (unsigned short)u;
}

// XCD-aware n-swizzle (R7: cut cc FETCH 605->140 MB). Bijection on [0,101).
__device__ __forceinline__ int swz_n(int L) {
  int q = L & 7, r = L >> 3;
  return q * 13 - (q > 5 ? (q - 5) : 0) + r;
}

// ---------------------------------------------------------------------------
// K1: LSTM (R7 version, unchanged). 16 lanes per pair of rows, vf2-packed.
// ---------------------------------------------------------------------------
__global__ __launch_bounds__(256) void lstm_kernel(
    const float* __restrict__ x, const float* __restrict__ pw,
    const float* __restrict__ pb, const float* __restrict__ w_ih,
    const float* __restrict__ w_hh, const float* __restrict__ b_ih,
    const float* __restrict__ b_hh, float* __restrict__ h_out) {
  const int tid = threadIdx.x;
  const int lane = tid & 63;
  const int sub = lane >> 4;
  const int k = lane & 15;
  const int wave = tid >> 6;
  const int row = blockIdx.x * 32 + wave * 8 + sub * 2;

  float wih[4][4], whh[4][16], bias[4];
#pragma unroll
  for (int q = 0; q < 4; q++) {
    const int j = q * 16 + k;
    bias[q] = b_ih[j] + b_hh[j];
#pragma unroll
    for (int jj = 0; jj < 4; jj++) wih[q][jj] = w_ih[j * 4 + jj];
#pragma unroll
    for (int m = 0; m < 16; m++) whh[q][m] = w_hh[j * 16 + m];
  }
  float pwr[16], pbr[4];
#pragma unroll
  for (int i = 0; i < 16; i++) pwr[i] = pw[i];
#pragma unroll
  for (int i = 0; i < 4; i++) pbr[i] = pb[i];

  vf2 h = {0.f, 0.f}, c = {0.f, 0.f};
  const float4* xpA = (const float4*)x + (size_t)row * T;
  const float4* xpB = xpA + T;
  const int base = sub * 16;

#pragma unroll 1
  for (int t = 0; t < T; t++) {
    float4 xa = xpA[t];
    float4 xb = xpB[t];
    vf2 xv[4];
#pragma unroll
    for (int j = 0; j < 4; j++) {
      vf2 v = {pbr[j], pbr[j]};
      v += pwr[j * 4 + 0] * (vf2){xa.x, xb.x};
      v += pwr[j * 4 + 1] * (vf2){xa.y, xb.y};
      v += pwr[j * 4 + 2] * (vf2){xa.z, xb.z};
      v += pwr[j * 4 + 3] * (vf2){xa.w, xb.w};
      xv[j] = v;
    }
    vf2 a0 = {bias[0], bias[0]}, a1 = {bias[1], bias[1]};
    vf2 a2 = {bias[2], bias[2]}, a3 = {bias[3], bias[3]};
#pragma unroll
    for (int j = 0; j < 4; j++) {
      a0 += wih[0][j] * xv[j];
      a1 += wih[1][j] * xv[j];
      a2 += wih[2][j] * xv[j];
      a3 += wih[3][j] * xv[j];
    }
#pragma unroll
    for (int m = 0; m < 16; m++) {
      vf2 hm;
      hm.x = __shfl(h.x, base + m, 64);
      hm.y = __shfl(h.y, base + m, 64);
      a0 += whh[0][m] * hm;
      a1 += whh[1][m] * hm;
      a2 += whh[2][m] * hm;
      a3 += whh[3][m] * hm;
    }
    vf2 ig, fg, gg, og, tc;
    ig.x = sigmoidf_(a0.x); ig.y = sigmoidf_(a0.y);
    fg.x = sigmoidf_(a1.x); fg.y = sigmoidf_(a1.y);
    gg.x = tanhf_(a2.x);    gg.y = tanhf_(a2.y);
    og.x = sigmoidf_(a3.x); og.y = sigmoidf_(a3.y);
    c = fg * c + ig * gg;
    tc.x = tanhf_(c.x);     tc.y = tanhf_(c.y);
    h = og * tc;
  }
  h_out[(size_t)row * 16 + k] = h.x;
  h_out[(size_t)(row + 1) * 16 + k] = h.y;
}

// ---------------------------------------------------------------------------
// Prep: pack cc conv weights into MFMA A-fragment order (bf16).
// A[m=lane&15][k=quad*8+j]. Stage1 (C=8): k=(dn_local*8+ci), 4 dn/MFMA, 3 sets.
// Stage2/3 (C=16): k=(dn_local*16+ci), 2 dn/MFMA, 6 sets each.
// apk layout: [set 0..14][lane 0..63][j 0..7] ushort.
// ---------------------------------------------------------------------------
__global__ void prep_kernel(const float* __restrict__ t1c,
                            const float* __restrict__ t2c,
                            const float* __restrict__ t3c,
                            unsigned short* __restrict__ apk) {
  const int L = threadIdx.x;  // 64 threads
  const int co = L & 15, q = L >> 4;
#pragma unroll 1
  for (int set = 0; set < 15; set++) {
    int s, p;
    if (set < 3) { s = 0; p = set; }
    else if (set < 9) { s = 1; p = set - 3; }
    else { s = 2; p = set - 9; }
    u8v f;
#pragma unroll
    for (int j = 0; j < 8; j++) {
      float val = 0.f;
      if (s == 0) {
        int dn = p * 4 + q, ci = j;
        if (co < 8 && dn < 11) val = t1c[(co * 8 + ci) * 11 + dn];
      } else {
        int dn = p * 2 + (q >> 1), ci = (q & 1) * 8 + j;
        const float* w = (s == 1) ? t2c : t3c;
        if (dn < 11) val = w[(co * 16 + ci) * 11 + dn];
      }
      f[j] = f2bf(val);
    }
    *(u8v*)&apk[(set * 64 + L) * 8] = f;
  }
}

// ---------------------------------------------------------------------------
// K2/K4/K6: fused d1(relu)+d2(relu), causal dilated 1x3 over T. Streaming
// (R5-proven). Output now bf16 channel-interleaved [by][n][t][CO] for MFMA cc.
// ---------------------------------------------------------------------------
template <int CI, int CO, int DIL, bool FIRST>
__global__ __launch_bounds__(128) void d12_kernel(
    const float* __restrict__ xin,
    const float* __restrict__ pw, const float* __restrict__ pb,
    const float* __restrict__ w1, const float* __restrict__ w2,
    unsigned short* __restrict__ out, int b0) {
  const int t = threadIdx.x;
  const int n = swz_n(blockIdx.x), by = blockIdx.y;

  float r1[3][CO];
#pragma unroll
  for (int u = 0; u < 3; u++)
#pragma unroll
    for (int co = 0; co < CO; co++) r1[u][co] = 0.f;

  if constexpr (FIRST) {
    const int b = b0 + by;
    const float4* xp = (const float4*)xin + ((size_t)b * N + n) * T;
    float px[5][4];
#pragma unroll
    for (int v = 0; v < 5; v++) {
      int idx = t - v * DIL;
      float4 xr = xp[idx < 0 ? 0 : idx];
      bool ok = idx >= 0;
      px[v][0] = ok ? pb[0] + pw[0] * xr.x + pw[1] * xr.y + pw[2] * xr.z + pw[3] * xr.w : 0.f;
      px[v][1] = ok ? pb[1] + pw[4] * xr.x + pw[5] * xr.y + pw[6] * xr.z + pw[7] * xr.w : 0.f;
      px[v][2] = ok ? pb[2] + pw[8] * xr.x + pw[9] * xr.y + pw[10] * xr.z + pw[11] * xr.w : 0.f;
      px[v][3] = ok ? pb[3] + pw[12] * xr.x + pw[13] * xr.y + pw[14] * xr.z + pw[15] * xr.w : 0.f;
    }
#pragma unroll
    for (int ci = 0; ci < CI; ci++) {
#pragma unroll
      for (int j = 0; j < 3; j++) {
#pragma unroll
        for (int co = 0; co < CO; co++) {
          float w = w1[(co * CI + ci) * 3 + j];
#pragma unroll
          for (int u = 0; u < 3; u++) r1[u][co] += w * px[u + 2 - j][ci];
        }
      }
    }
  } else {
#pragma unroll
    for (int ci = 0; ci < CI; ci++) {
      const float* xp = xin + (((size_t)by * CI + ci) * N + n) * T;
      float xt[5];
#pragma unroll
      for (int v = 0; v < 5; v++) {
        int idx = t - v * DIL;
        float xv = xp[idx < 0 ? 0 : idx];
        xt[v] = (idx >= 0) ? xv : 0.f;
      }
#pragma unroll
      for (int j = 0; j < 3; j++) {
#pragma unroll
        for (int co = 0; co < CO; co++) {
          float w = w1[(co * CI + ci) * 3 + j];
#pragma unroll
          for (int u = 0; u < 3; u++) r1[u][co] += w * xt[u + 2 - j];
        }
      }
    }
  }

#pragma unroll
  for (int u = 0; u < 3; u++)
#pragma unroll
    for (int co = 0; co < CO; co++) r1[u][co] = fmaxf(r1[u][co], 0.f);

  float acc[CO];
#pragma unroll
  for (int co = 0; co < CO; co++) acc[co] = 0.f;
#pragma unroll
  for (int cm = 0; cm < CO; cm++) {
#pragma unroll
    for (int j = 0; j < 3; j++) {
#pragma unroll
      for (int co = 0; co < CO; co++)
        acc[co] += w2[(co * CO + cm) * 3 + j] * r1[2 - j][cm];
    }
  }
  // bf16 interleaved store: [by][n][t][CO]
  unsigned short* op = &out[(((size_t)by * N + n) * T + t) * CO];
#pragma unroll
  for (int c8 = 0; c8 < CO / 8; c8++) {
    u8v a;
#pragma unroll
    for (int j = 0; j < 8; j++) a[j] = f2bf(fmaxf(acc[c8 * 8 + j], 0.f));
    *(u8v*)&op[c8 * 8] = a;
  }
}

// ---------------------------------------------------------------------------
// K3/K5/K7: cross-stock 11x1 conv via MFMA (D = 16co x 16t per wave).
// zin: bf16 [by][n][t][C]; A pre-packed (prep_kernel). K packs (dn_local,ci);
// OOB n-rows zeroed in B-frag; dn>=11 zeroed in A. Epilogue fp32: relu,
// residual, relu; writes fp32 planar [by][co][n][t].
// RESMODE: 0 = x-proj+rw (C=8), 1 = rw from H (CIR ch), 2 = identity.
// ---------------------------------------------------------------------------
template <int C, int CIR, int RESMODE>
__global__ __launch_bounds__(64) void ccm_kernel(
    const unsigned short* __restrict__ zin,  // [Bc][N][T][C] bf16
    const unsigned short* __restrict__ apk,  // [NMF][64][8] bf16
    const float* __restrict__ resin,         // RESMODE 0: x; else fp32 planar
    const float* __restrict__ rw,
    const float* __restrict__ pw, const float* __restrict__ pb,
    float* __restrict__ out,                 // fp32 planar [Bc][C][N][T]
    int b0) {
  constexpr int NMF = (C == 8) ? 3 : 6;
  const int L = threadIdx.x;
  const int tcol = L & 15, q = L >> 4;
  const int n = swz_n(blockIdx.x);
  const int t = blockIdx.y * 16 + tcol;
  const int by = blockIdx.z;
  const int b = b0 + by;

  f4v d = {0.f, 0.f, 0.f, 0.f};
#pragma unroll
  for (int p = 0; p < NMF; p++) {
    // B fragment: 8 contiguous ci at row n+dn-5, this lane's t
    int dn = (C == 8) ? (p * 4 + q) : (p * 2 + (q >> 1));
    int row = n + dn - 5;
    bool ok = (unsigned)row < (unsigned)N;
    int rowc = ok ? row : 0;
    const unsigned short* bp =
        &zin[(((size_t)by * N + rowc) * T + t) * C + ((C == 16) ? (q & 1) * 8 : 0)];
    s8v bfrag = *(const s8v*)bp;
    if (!ok) bfrag = (s8v){0, 0, 0, 0, 0, 0, 0, 0};
    s8v afrag = *(const s8v*)&apk[(p * 64 + L) * 8];
    d = __builtin_amdgcn_mfma_f32_16x16x32_bf16(afrag, bfrag, d, 0, 0, 0);
  }

  // Epilogue: lane holds conv[co = q*4+r][t], r=0..3
  if (C == 8 && q >= 2) return;  // rows 8..15 unused for C=8

  float y[4];
  if constexpr (RESMODE == 0) {
    float4 xr = ((const float4*)resin)[((size_t)b * N + n) * T + t];
    float xv[4];
#pragma unroll
    for (int j = 0; j < 4; j++)
      xv[j] = pb[j] + pw[j * 4 + 0] * xr.x + pw[j * 4 + 1] * xr.y +
              pw[j * 4 + 2] * xr.z + pw[j * 4 + 3] * xr.w;
#pragma unroll
    for (int r = 0; r < 4; r++) {
      int co = q * 4 + r;
      float rv = rw[co * 4 + 0] * xv[0] + rw[co * 4 + 1] * xv[1] +
                 rw[co * 4 + 2] * xv[2] + rw[co * 4 + 3] * xv[3];
      y[r] = fmaxf(rv + fmaxf(d[r], 0.f), 0.f);
    }
  } else if constexpr (RESMODE == 1) {
    float hv[CIR];
#pragma unroll
    for (int ci = 0; ci < CIR; ci++)
      hv[ci] = resin[(((size_t)by * CIR + ci) * N + n) * T + t];
#pragma unroll
    for (int r = 0; r < 4; r++) {
      int co = q * 4 + r;
      float rv = 0.f;
#pragma unroll
      for (int ci = 0; ci < CIR; ci++) rv += rw[co * CIR + ci] * hv[ci];
      y[r] = fmaxf(rv + fmaxf(d[r], 0.f), 0.f);
    }
  } else {
#pragma unroll
    for (int r = 0; r < 4; r++) {
      int co = q * 4 + r;
      float rv = resin[(((size_t)by * C + co) * N + n) * T + t];
      y[r] = fmaxf(rv + fmaxf(d[r], 0.f), 0.f);
    }
  }
#pragma unroll
  for (int r = 0; r < 4; r++) {
    int co = q * 4 + r;
    out[(((size_t)by * C + co) * N + n) * T + t] = y[r];
  }
}

// ---------------------------------------------------------------------------
// conv4: h4[b][o][n] = relu(sum_{ci,t} w4[o][ci][t] * Y[ci][t]).
// One 64-lane wave per (b,n), t-pairs, vf2. Streaming (R7-proven regime).
// ---------------------------------------------------------------------------
__global__ __launch_bounds__(64) void conv4_kernel(
    const float* __restrict__ Y,   // [Bc][16][N][T]
    const float* __restrict__ w4,  // [16][16][T]
    float* __restrict__ h4,        // [B][16][N]
    int b0) {
  const int tl = threadIdx.x;
  const int n = blockIdx.x, by = blockIdx.y;
  const int b = b0 + by;
  const int t0 = tl * 2;

  vf2 y[16];
#pragma unroll
  for (int ci = 0; ci < 16; ci++)
    y[ci] = *(const vf2*)&Y[(((size_t)by * 16 + ci) * N + n) * T + t0];

#pragma unroll 1
  for (int o = 0; o < 16; o++) {
    vf2 s = (vf2)0.f;
#pragma unroll
    for (int ci = 0; ci < 16; ci++) {
      vf2 w = *(const vf2*)&w4[(size_t)(o * 16 + ci) * T + t0];
      s += w * y[ci];
    }
    float sum = s.x + s.y;
    sum += __shfl_down(sum, 32);
    sum += __shfl_down(sum, 16);
    sum += __shfl_down(sum, 8);
    sum += __shfl_down(sum, 4);
    sum += __shfl_down(sum, 2);
    sum += __shfl_down(sum, 1);
    if (tl == 0) h4[((size_t)b * 16 + o) * N + n] = fmaxf(sum, 0.f);
  }
}

// ---------------------------------------------------------------------------
// K8: logits (torch reshape scramble) + softmax over N
// ---------------------------------------------------------------------------
__global__ __launch_bounds__(128) void final_kernel(
    const float* __restrict__ hl, const float* __restrict__ h4,
    const float* __restrict__ ow, const float* __restrict__ ob,
    float* __restrict__ out) {
  __shared__ float red[128];
  int b = blockIdx.x, n = threadIdx.x;
  bool valid = n < N;
  float lv = 0.f;
  if (valid) {
    int idx = b * N + n;
    int sb = idx & (B - 1);
    int sn = idx >> 8;
    const float* h = &hl[((size_t)sb * N + sn) * 16];
    float a = ob[0];
#pragma unroll
    for (int k = 0; k < 16; k++) a += h[k] * ow[k];
#pragma unroll
    for (int c = 0; c < 16; c++) a += h4[((size_t)b * 16 + c) * N + n] * ow[16 + c];
    lv = a;
  }
  red[n] = valid ? lv : -1e30f;
  __syncthreads();
  for (int off = 64; off > 0; off >>= 1) {
    if (n < off) red[n] = fmaxf(red[n], red[n + off]);
    __syncthreads();
  }
  float m = red[0];
  __syncthreads();
  float e = valid ? __expf(lv - m) : 0.f;
  red[n] = e;
  __syncthreads();
  for (int off = 64; off > 0; off >>= 1) {
    if (n < off) red[n] += red[n + off];
    __syncthreads();
  }
  float s = red[0];
  if (valid) out[(size_t)b * N + n] = e / s;
}

// ---------------------------------------------------------------------------
// Launch. Chunked over B. Per-b unit: Zb1(4) + H1(8) + Zb2(8) + H2(16) +
// Y3(16) = 52*NT floats. Zb3 aliases Zb2 (stream-ordered).
// ---------------------------------------------------------------------------
extern "C" void kernel_launch(void* const* d_in, const int* in_sizes, int n_in,
                              void* d_out, int out_size, void* d_ws, size_t ws_size,
                              hipStream_t stream) {
  const float* x    = (const float*)d_in[0];
  const float* pw   = (const float*)d_in[1];
  const float* pb   = (const float*)d_in[2];
  const float* w_ih = (const float*)d_in[3];
  const float* w_hh = (const float*)d_in[4];
  const float* b_ih = (const float*)d_in[5];
  const float* b_hh = (const float*)d_in[6];
  const float* t1d1 = (const float*)d_in[7];
  const float* t1d2 = (const float*)d_in[8];
  const float* t1c  = (const float*)d_in[9];
  const float* t1r  = (const float*)d_in[10];
  const float* t2d1 = (const float*)d_in[11];
  const float* t2d2 = (const float*)d_in[12];
  const float* t2c  = (const float*)d_in[13];
  const float* t2r  = (const float*)d_in[14];
  const float* t3d1 = (const float*)d_in[15];
  const float* t3d2 = (const float*)d_in[16];
  const float* t3c  = (const float*)d_in[17];
  const float* w4   = (const float*)d_in[18];
  const float* ow   = (const float*)d_in[19];
  const float* ob   = (const float*)d_in[20];
  float* outp = (float*)d_out;

  const size_t NT = (size_t)N * T;            // 12928
  const size_t Bn16 = (size_t)B * N * 16;
  const size_t unit = 52 * NT;                // floats per chunked b
  const size_t fixed = 2 * Bn16 + 4096;       // hl + h4 + apk

  int Bc = 4;
  const int cands[7] = {256, 128, 64, 32, 16, 8, 4};
  for (int i = 0; i < 7; i++) {
    if ((cands[i] * unit + fixed) * sizeof(float) <= ws_size) { Bc = cands[i]; break; }
  }

  float* ws = (float*)d_ws;
  float* hl = ws;                              // [B*N][16]
  float* h4 = hl + Bn16;                       // [B][16][N]
  unsigned short* apk = (unsigned short*)(h4 + Bn16);  // 15*64*8 ushorts
  float* base = h4 + Bn16 + 4096;
  unsigned short* Zb1 = (unsigned short*)base;            // [Bc][N][T][8] bf16
  float* H1 = base + (size_t)Bc * 4 * NT;                 // [Bc][8][N][T]
  unsigned short* Zb2 = (unsigned short*)(H1 + (size_t)Bc * 8 * NT);  // [Bc][N][T][16]
  float* H2 = H1 + (size_t)Bc * 16 * NT;                  // [Bc][16][N][T]
  float* Y3 = H2 + (size_t)Bc * 16 * NT;                  // [Bc][16][N][T]

  prep_kernel<<<1, 64, 0, stream>>>(t1c, t2c, t3c, apk);
  lstm_kernel<<<(B * N) / 32, 256, 0, stream>>>(x, pw, pb, w_ih, w_hh, b_ih,
                                                b_hh, hl);

  dim3 g(N, Bc);
  dim3 gm(N, T / 16, Bc);
  for (int b0 = 0; b0 < B; b0 += Bc) {
    d12_kernel<4, 8, 1, true>
        <<<g, 128, 0, stream>>>(x, pw, pb, t1d1, t1d2, Zb1, b0);
    ccm_kernel<8, 4, 0><<<gm, 64, 0, stream>>>(
        Zb1, apk + 0 * 512, x, t1r, pw, pb, H1, b0);

    d12_kernel<8, 16, 2, false>
        <<<g, 128, 0, stream>>>(H1, pw, pb, t2d1, t2d2, Zb2, b0);
    ccm_kernel<16, 8, 1><<<gm, 64, 0, stream>>>(
        Zb2, apk + 3 * 512, H1, t2r, pw, pb, H2, b0);

    d12_kernel<16, 16, 4, false>
        <<<g, 128, 0, stream>>>(H2, pw, pb, t3d1, t3d2, Zb2, b0);
    ccm_kernel<16, 16, 2><<<gm, 64, 0, stream>>>(
        Zb2, apk + 9 * 512, H2, nullptr, pw, pb, Y3, b0);

    conv4_kernel<<<g, 64, 0, stream>>>(Y3, w4, h4, b0);
  }

  final_kernel<<<B, 128, 0, stream>>>(hl, h4, ow, ob, outp);
}